// Round 12
// baseline (24968.549 us; speedup 1.0000x reference)
//
#include <hip/hip_runtime.h>

#define Bb 512
#define Tt 512
#define Ll 256
#define Ff 256
#define Hh 128
#define H3 384
#define NZ 8
#define XC 16
#define OC 8
#define CF 9
#define W3N 1152
#define BBt 2     // batches per CDE block -> 256 blocks (1/CU)

__device__ __forceinline__ float sigm(float x){ return 1.0f/(1.0f+expf(-x)); }
__device__ __forceinline__ float softplus_(float x){
  return fmaxf(x, 0.0f) + log1pf(expf(-fabsf(x)));
}
__device__ __forceinline__ float dot4(float4 w, float4 z){
  return w.x*z.x + w.y*z.y + w.z*z.z + w.w*z.w;
}
// involutive float4-index swizzle for [32]-float4 state rows
__device__ __forceinline__ int swz32(int i){ return i ^ ((i >> 3) & 3); }
__device__ __forceinline__ int swzf(int h){ return (((h >> 2) ^ ((h >> 5) & 3)) << 2) + (h & 3); }

// ---------------- GRU v2: 768 threads, 2 threads per gate-row (unchanged) -----
__global__ __launch_bounds__(768) void gru_kernel(
    const float* __restrict__ xin, const float* __restrict__ zx_in,
    const float* __restrict__ tin,
    const float* __restrict__ wih, const float* __restrict__ whh,
    const float* __restrict__ bias, const float* __restrict__ bn,
    const float* __restrict__ zxlw, const float* __restrict__ zxlb,
    float* __restrict__ out_zx, float* __restrict__ out_h,
    int steps, int mode)
{
  const int b = blockIdx.x;
  const int tid = threadIdx.x;
  const int j = tid >> 1;
  const int half = tid & 1;

  float wi[17];
  #pragma unroll
  for (int c = 0; c < 17; c++) wi[c] = wih[j*17 + c];
  const float bj = bias[j];
  float4 wr[16];
  {
    const float4* p = reinterpret_cast<const float4*>(whh + (size_t)j*Hh + half*64);
    #pragma unroll
    for (int q = 0; q < 16; q++) wr[q] = p[q];
  }

  __shared__ __align__(16) float s_h[Hh];
  __shared__ float s_i[H3];
  __shared__ float s_g[H3];
  __shared__ float s_x[17];
  __shared__ float s_bn[Hh];
  __shared__ float s_zxlw[NZ*Hh];
  __shared__ float s_red[NZ][17];

  if (tid < Hh){ s_h[tid] = 0.0f; s_bn[tid] = bn[tid]; }
  if (mode == 0){ for (int q = tid; q < NZ*Hh; q += 768) s_zxlw[q] = zxlw[q]; }
  __syncthreads();

  for (int t = 0; t < steps; t++){
    if (mode == 0){
      if (tid < 16) s_x[tid] = xin[(size_t)b*Tt*XC + (size_t)t*XC + tid];
      else if (tid == 16) s_x[16] = tin[t];
    } else {
      if (tid < 8) s_x[tid] = xin[(size_t)b*Ll*NZ + (size_t)t*NZ + tid];
      else if (tid < 16) s_x[tid] = zx_in[(size_t)b*Tt*NZ + (size_t)t*NZ + (tid - 8)];
      else if (tid == 16) s_x[16] = tin[t];
    }
    __syncthreads();
    float ai = bj;
    #pragma unroll
    for (int c = 0; c < 17; c++) ai += wi[c]*s_x[c];
    float g0=0.f, g1=0.f, g2=0.f, g3=0.f;
    {
      const float4* h4p = reinterpret_cast<const float4*>(&s_h[half*64]);
      #pragma unroll
      for (int q = 0; q < 16; q++){
        float4 w = wr[q];
        float4 h4 = h4p[q];
        g0 += w.x*h4.x; g1 += w.y*h4.y; g2 += w.z*h4.z; g3 += w.w*h4.w;
      }
    }
    float g = (g0+g1)+(g2+g3);
    g += __shfl_xor(g, 1, 64);
    if (half == 0){ s_i[j] = ai; s_g[j] = g; }
    __syncthreads();
    if (tid < Hh){
      float r  = sigm(s_i[tid]       + s_g[tid]);
      float zz = sigm(s_i[Hh + tid]  + s_g[Hh + tid]);
      float n  = tanhf(s_i[2*Hh+tid] + r*(s_g[2*Hh+tid] + s_bn[tid]));
      s_h[tid] = n + zz*(s_h[tid] - n);
    }
    __syncthreads();
    if (mode == 0){
      if (tid < Hh){
        int o = tid >> 4, m = tid & 15;
        float p = 0.f;
        #pragma unroll
        for (int q = 0; q < 8; q++) p += s_zxlw[o*Hh + m*8 + q]*s_h[m*8 + q];
        s_red[o][m] = p;
      }
      __syncthreads();
      if (tid < NZ){
        float p = zxlb[tid];
        #pragma unroll
        for (int m = 0; m < 16; m++) p += s_red[tid][m];
        out_zx[(size_t)b*Tt*NZ + (size_t)t*NZ + tid] = p;
      }
      __syncthreads();
    }
  }
  if (mode == 1 && tid < Hh) out_h[b*Hh + tid] = s_h[tid];
}

// ---------------- CDE RK4 v7 — warm cross-stage w3 stream pipeline -------------
// 256 blocks (1/CU) x 2 batches x 512 threads.
// w3 addresses identical every stage -> 3-deep prefetch ring stays warm ACROSS
// stages: G3 iters 15..17 issue next stage's tiles; they fly during B/dX/G1/G2.
// Phase A divisionless (c decrements mod 9; 512 = -1 mod 9, 1152 % 9 == 0).
__global__ __launch_bounds__(512)
__attribute__((amdgpu_waves_per_eu(2, 2)))
void cde_fp32_kernel(
    const float* __restrict__ zy_h, const float* __restrict__ zx,
    const float* __restrict__ tin,
    const float* __restrict__ fw1, const float* __restrict__ fb1,
    const float* __restrict__ fw2, const float* __restrict__ fb2,
    const float* __restrict__ fw3, const float* __restrict__ fb3,
    const float* __restrict__ rw,  const float* __restrict__ rb,
    float* __restrict__ yout)
{
  const int tid = threadIdx.x;
  const int c12 = tid >> 2;      // G1/G2: output col 0..127
  const int q4  = tid & 3;       // G1/G2: k-quarter
  const int col64 = tid >> 3;    // G3: col-in-group 0..63
  const int e8    = tid & 7;     // G3: k-eighth (16 floats)
  const int c9    = tid % 9;     // phase-A dx channel seed (one magic-mul)
  const int bg = blockIdx.x * BBt;

  __shared__ __align__(16) float4 s_w1v[4096];   // 64 KB, [jj][col*4+q4]
  __shared__ __align__(16) float4 s_w2v[4096];   // 64 KB
  __shared__ __align__(16) float4 s_zinv[BBt][32];  // swizzled state rows
  __shared__ __align__(16) float4 s_h1v[BBt][32];
  __shared__ __align__(16) float4 s_h2v[BBt][32];
  __shared__ float s_o[BBt][W3N];
  __shared__ float s_z[BBt][Hh];
  __shared__ float s_kacc[BBt][Hh];
  __shared__ float s_dx[BBt][CF];
  __shared__ float s_rw[OC*Hh];
  __shared__ float s_rb[OC];
  __shared__ float s_b3[W3N];

  float* zin_f0 = reinterpret_cast<float*>(&s_zinv[0][0]);
  float* zin_f1 = reinterpret_cast<float*>(&s_zinv[1][0]);
  float* h1_f0  = reinterpret_cast<float*>(&s_h1v[0][0]);
  float* h1_f1  = reinterpret_cast<float*>(&s_h1v[1][0]);
  float* h2_f0  = reinterpret_cast<float*>(&s_h2v[0][0]);
  float* h2_f1  = reinterpret_cast<float*>(&s_h2v[1][0]);
  float* s_of   = &s_o[0][0];

  // ---- one-time: w1/w2 -> [jj][col*4+q] layout; biases, readout, init ----
  for (int idx = tid; idx < Hh*32; idx += 512){
    int col = idx >> 5, jcol = idx & 31;
    int q = jcol >> 3, jj = jcol & 7;
    int dst = jj*512 + col*4 + q;
    s_w1v[dst] = reinterpret_cast<const float4*>(fw1)[idx];
    s_w2v[dst] = reinterpret_cast<const float4*>(fw2)[idx];
  }
  const float b1r = fb1[c12], b2r = fb2[c12];
  for (int idx = tid; idx < W3N; idx += 512) s_b3[idx] = fb3[idx];
  for (int idx = tid; idx < OC*Hh; idx += 512) s_rw[idx] = rw[idx];
  if (tid < OC) s_rb[tid] = rb[tid];
  if (tid < BBt*Hh){
    int b = tid >> 7, h = tid & 127;
    float zv = zy_h[(size_t)(bg + b)*Hh + h];
    s_z[b][h] = zv;
    (b == 0 ? zin_f0 : zin_f1)[swzf(h)] = zv;
  }
  __syncthreads();

  // y[:, 0, :]
  if (tid < 256){
    int b = tid >> 7, r = tid & 127, o = r >> 4, seg = r & 15;
    float p = 0.f;
    #pragma unroll
    for (int q = 0; q < 8; q++)
      p += s_z[b][seg*8 + q]*s_rw[o*Hh + seg*8 + q];
    p += __shfl_xor(p, 1, 64); p += __shfl_xor(p, 2, 64);
    p += __shfl_xor(p, 4, 64); p += __shfl_xor(p, 8, 64);
    if (seg == 0) yout[(size_t)(bg + b)*Ff*OC + o] = s_rb[o] + p;
  }

  const float* w3p = fw3 + (size_t)col64*Hh + e8*16;   // + g*8192 floats per iter

  // ---- prime 3-deep prefetch ring (stays warm across ALL stages/steps) ----
  float4 pb[3][4];
  #pragma unroll
  for (int g = 0; g < 3; g++){
    const float4* pP = reinterpret_cast<const float4*>(w3p + (size_t)g*8192);
    #pragma unroll
    for (int j = 0; j < 4; j++) pb[g][j] = pP[j];
  }

  for (int i = 0; i < Ff - 1; i++){
    if (tid < BBt*CF){
      int b = tid/CF, c = tid%CF;
      float d;
      if (c < 8){
        const float* zp = zx + (size_t)(bg + b)*Tt*NZ + (size_t)(Ll + i)*NZ + c;
        d = zp[NZ] - zp[0];
      } else {
        d = tin[Ll + i + 1] - tin[Ll + i];
      }
      s_dx[b][c] = d;
    }
    __syncthreads();

    for (int st = 0; st < 4; st++){
      // ---- G1: h1 = softplus(zin @ w1.T + b1) ----
      {
        float p0 = 0.f, p1 = 0.f;
        #pragma unroll
        for (int jj = 0; jj < 8; jj++){
          float4 z0 = s_zinv[0][swz32(q4*8 + jj)];
          float4 z1 = s_zinv[1][swz32(q4*8 + jj)];
          float4 w = s_w1v[jj*512 + tid];
          p0 += dot4(w, z0); p1 += dot4(w, z1);
        }
        p0 += __shfl_xor(p0, 1, 64); p0 += __shfl_xor(p0, 2, 64);
        p1 += __shfl_xor(p1, 1, 64); p1 += __shfl_xor(p1, 2, 64);
        if (q4 == 0){
          h1_f0[swzf(c12)] = softplus_(b1r + p0);
          h1_f1[swzf(c12)] = softplus_(b1r + p1);
        }
      }
      __syncthreads();
      // ---- G2 ----
      {
        float p0 = 0.f, p1 = 0.f;
        #pragma unroll
        for (int jj = 0; jj < 8; jj++){
          float4 z0 = s_h1v[0][swz32(q4*8 + jj)];
          float4 z1 = s_h1v[1][swz32(q4*8 + jj)];
          float4 w = s_w2v[jj*512 + tid];
          p0 += dot4(w, z0); p1 += dot4(w, z1);
        }
        p0 += __shfl_xor(p0, 1, 64); p0 += __shfl_xor(p0, 2, 64);
        p1 += __shfl_xor(p1, 1, 64); p1 += __shfl_xor(p1, 2, 64);
        if (q4 == 0){
          h2_f0[swzf(c12)] = softplus_(b2r + p0);
          h2_f1[swzf(c12)] = softplus_(b2r + p1);
        }
      }
      __syncthreads();
      // ---- G3: 18 iters fully unrolled; consume pb[g%3], reload for g+3 ----
      {
        float4 h2a0 = s_h2v[0][swz32(e8*4 + 0)];
        float4 h2a1 = s_h2v[0][swz32(e8*4 + 1)];
        float4 h2a2 = s_h2v[0][swz32(e8*4 + 2)];
        float4 h2a3 = s_h2v[0][swz32(e8*4 + 3)];
        float4 h2b0 = s_h2v[1][swz32(e8*4 + 0)];
        float4 h2b1 = s_h2v[1][swz32(e8*4 + 1)];
        float4 h2b2 = s_h2v[1][swz32(e8*4 + 2)];
        float4 h2b3 = s_h2v[1][swz32(e8*4 + 3)];
        #pragma unroll
        for (int g = 0; g < 18; g++){
          const int sl = g % 3;                       // constant after unroll
          float4 c0 = pb[sl][0], c1 = pb[sl][1], c2 = pb[sl][2], c3 = pb[sl][3];
          {
            const int gl = (g + 3 < 18) ? (g + 3) : (g + 3 - 18);  // wrap -> next stage warm
            const float4* pF = reinterpret_cast<const float4*>(w3p + (size_t)gl*8192);
            pb[sl][0] = pF[0]; pb[sl][1] = pF[1]; pb[sl][2] = pF[2]; pb[sl][3] = pF[3];
          }
          float p0 = dot4(c0, h2a0) + dot4(c1, h2a1) + dot4(c2, h2a2) + dot4(c3, h2a3);
          float p1 = dot4(c0, h2b0) + dot4(c1, h2b1) + dot4(c2, h2b2) + dot4(c3, h2b3);
          p0 += __shfl_xor(p0, 1, 64); p0 += __shfl_xor(p0, 2, 64); p0 += __shfl_xor(p0, 4, 64);
          p1 += __shfl_xor(p1, 1, 64); p1 += __shfl_xor(p1, 2, 64); p1 += __shfl_xor(p1, 4, 64);
          if (e8 == 0){
            int n = g*64 + col64;
            s_o[0][n] = s_b3[n] + p0;
            s_o[1][n] = s_b3[n] + p1;
          }
        }
      }
      __syncthreads();
      // ---- phase A: o <- tanh(o) * dx[c], divisionless ----
      {
        int cc = c9;
        #pragma unroll
        for (int k = 0; k < 5; k++){
          int v = tid + k*512;
          if (v < BBt*W3N){
            int b = (v >= W3N) ? 1 : 0;
            s_of[v] = tanhf(s_of[v]) * s_dx[b][cc];
          }
          cc = (cc == 0) ? 8 : cc - 1;   // +512 = -1 mod 9
        }
      }
      __syncthreads();
      // ---- phase B: k_h = sum_c + RK4 combine ----
      if (tid < BBt*Hh){
        int b = tid >> 7, h = tid & 127;
        float kc = 0.f;
        #pragma unroll
        for (int c = 0; c < CF; c++) kc += s_o[b][h*CF + c];
        float zv = s_z[b][h], zin;
        if      (st == 0){ s_kacc[b][h] = kc;        zin = zv + 0.5f*kc; }
        else if (st == 1){ s_kacc[b][h] += 2.f*kc;   zin = zv + 0.5f*kc; }
        else if (st == 2){ s_kacc[b][h] += 2.f*kc;   zin = zv + kc; }
        else { float zn = zv + (s_kacc[b][h] + kc)*(1.f/6.f); s_z[b][h] = zn; zin = zn; }
        (b == 0 ? zin_f0 : zin_f1)[swzf(h)] = zin;
      }
      __syncthreads();
    }
    // readout y[:, i+1, :]
    if (tid < 256){
      int b = tid >> 7, r = tid & 127, o = r >> 4, seg = r & 15;
      float p = 0.f;
      #pragma unroll
      for (int q = 0; q < 8; q++)
        p += s_z[b][seg*8 + q]*s_rw[o*Hh + seg*8 + q];
      p += __shfl_xor(p, 1, 64); p += __shfl_xor(p, 2, 64);
      p += __shfl_xor(p, 4, 64); p += __shfl_xor(p, 8, 64);
      if (seg == 0) yout[(size_t)(bg + b)*Ff*OC + (size_t)(i + 1)*OC + o] = s_rb[o] + p;
    }
  }
}

extern "C" void kernel_launch(void* const* d_in, const int* in_sizes, int n_in,
                              void* d_out, int out_size, void* d_ws, size_t ws_size,
                              hipStream_t stream)
{
  (void)in_sizes; (void)n_in; (void)out_size; (void)ws_size;
  const float* y_past = (const float*)d_in[0];
  const float* t_in   = (const float*)d_in[1];
  const float* coeffs = (const float*)d_in[2];
  // d_in[3] = input_length (fixed 256)
  const float* zx_wih = (const float*)d_in[4];
  const float* zx_whh = (const float*)d_in[5];
  const float* zx_b   = (const float*)d_in[6];
  const float* zx_bn  = (const float*)d_in[7];
  const float* zxl_w  = (const float*)d_in[8];
  const float* zxl_b  = (const float*)d_in[9];
  const float* zy_wih = (const float*)d_in[10];
  const float* zy_whh = (const float*)d_in[11];
  const float* zy_b   = (const float*)d_in[12];
  const float* zy_bn  = (const float*)d_in[13];
  const float* fw1 = (const float*)d_in[14];
  const float* fb1 = (const float*)d_in[15];
  const float* fw2 = (const float*)d_in[16];
  const float* fb2 = (const float*)d_in[17];
  const float* fw3 = (const float*)d_in[18];
  const float* fb3 = (const float*)d_in[19];
  const float* r_w = (const float*)d_in[20];
  const float* r_b = (const float*)d_in[21];

  float* ws = (float*)d_ws;
  float* zx_buf = ws;                              // B*T*NZ fp32 = 8.39 MB
  float* zy_buf = ws + (size_t)Bb*Tt*NZ;           // B*H fp32   = 256 KB

  gru_kernel<<<Bb, 768, 0, stream>>>(coeffs, nullptr, t_in,
                                     zx_wih, zx_whh, zx_b, zx_bn,
                                     zxl_w, zxl_b, zx_buf, nullptr, Tt, 0);
  gru_kernel<<<Bb, 768, 0, stream>>>(y_past, zx_buf, t_in,
                                     zy_wih, zy_whh, zy_b, zy_bn,
                                     nullptr, nullptr, nullptr, zy_buf, Ll, 1);
  cde_fp32_kernel<<<Bb/BBt, 512, 0, stream>>>(zy_buf, zx_buf, t_in,
                                              fw1, fb1, fw2, fb2, fw3, fb3,
                                              r_w, r_b, (float*)d_out);
}

// Round 13
// 14471.791 us; speedup vs baseline: 1.7253x; 1.7253x over previous
//
#include <hip/hip_runtime.h>

#define Bb 512
#define Tt 512
#define Ll 256
#define Ff 256
#define Hh 128
#define H3 384
#define NZ 8
#define XC 16
#define OC 8
#define CF 9
#define W3N 1152
#define BBt 2     // batches per CDE block -> 256 blocks (1/CU)

__device__ __forceinline__ float sigm(float x){ return 1.0f/(1.0f+expf(-x)); }
__device__ __forceinline__ float softplus_(float x){
  return fmaxf(x, 0.0f) + log1pf(expf(-fabsf(x)));
}
__device__ __forceinline__ float dot4(float4 w, float4 z){
  return w.x*z.x + w.y*z.y + w.z*z.z + w.w*z.w;
}
// involutive float4-index swizzle for [32]-float4 state rows
__device__ __forceinline__ int swz32(int i){ return i ^ ((i >> 3) & 3); }
__device__ __forceinline__ int swzf(int h){ return (((h >> 2) ^ ((h >> 5) & 3)) << 2) + (h & 3); }

// ---------------- GRU v3: 768 threads, 2/row, 1-step x-prefetch ----------------
__global__ __launch_bounds__(768) void gru_kernel(
    const float* __restrict__ xin, const float* __restrict__ zx_in,
    const float* __restrict__ tin,
    const float* __restrict__ wih, const float* __restrict__ whh,
    const float* __restrict__ bias, const float* __restrict__ bn,
    const float* __restrict__ zxlw, const float* __restrict__ zxlb,
    float* __restrict__ out_zx, float* __restrict__ out_h,
    int steps, int mode)
{
  const int b = blockIdx.x;
  const int tid = threadIdx.x;
  const int j = tid >> 1;
  const int half = tid & 1;

  float wi[17];
  #pragma unroll
  for (int c = 0; c < 17; c++) wi[c] = wih[j*17 + c];
  const float bj = bias[j];
  float4 wr[16];
  {
    const float4* p = reinterpret_cast<const float4*>(whh + (size_t)j*Hh + half*64);
    #pragma unroll
    for (int q = 0; q < 16; q++) wr[q] = p[q];
  }

  __shared__ __align__(16) float s_h[Hh];
  __shared__ float s_i[H3];
  __shared__ float s_g[H3];
  __shared__ float s_x[17];
  __shared__ float s_bn[Hh];
  __shared__ float s_zxlw[NZ*Hh];
  __shared__ float s_red[NZ][17];

  if (tid < Hh){ s_h[tid] = 0.0f; s_bn[tid] = bn[tid]; }
  if (mode == 0){ for (int q = tid; q < NZ*Hh; q += 768) s_zxlw[q] = zxlw[q]; }

  // prefetch x(0) into regs
  float xreg = 0.f;
  if (tid < 17){
    if (mode == 0){
      xreg = (tid < 16) ? xin[(size_t)b*Tt*XC + tid] : tin[0];
    } else {
      if (tid < 8)       xreg = xin[(size_t)b*Ll*NZ + tid];
      else if (tid < 16) xreg = zx_in[(size_t)b*Tt*NZ + (tid - 8)];
      else               xreg = tin[0];
    }
  }
  __syncthreads();

  for (int t = 0; t < steps; t++){
    if (tid < 17) s_x[tid] = xreg;
    __syncthreads();
    float ai = bj;
    #pragma unroll
    for (int c = 0; c < 17; c++) ai += wi[c]*s_x[c];
    float g0=0.f, g1=0.f, g2=0.f, g3=0.f;
    {
      const float4* h4p = reinterpret_cast<const float4*>(&s_h[half*64]);
      #pragma unroll
      for (int q = 0; q < 16; q++){
        float4 w = wr[q];
        float4 h4 = h4p[q];
        g0 += w.x*h4.x; g1 += w.y*h4.y; g2 += w.z*h4.z; g3 += w.w*h4.w;
      }
    }
    float g = (g0+g1)+(g2+g3);
    g += __shfl_xor(g, 1, 64);
    if (half == 0){ s_i[j] = ai; s_g[j] = g; }
    // issue prefetch of x(t+1) now — arrives during barriers + h-update
    if (tid < 17 && t + 1 < steps){
      const int tn = t + 1;
      if (mode == 0){
        xreg = (tid < 16) ? xin[(size_t)b*Tt*XC + (size_t)tn*XC + tid] : tin[tn];
      } else {
        if (tid < 8)       xreg = xin[(size_t)b*Ll*NZ + (size_t)tn*NZ + tid];
        else if (tid < 16) xreg = zx_in[(size_t)b*Tt*NZ + (size_t)tn*NZ + (tid - 8)];
        else               xreg = tin[tn];
      }
    }
    __syncthreads();
    if (tid < Hh){
      float r  = sigm(s_i[tid]       + s_g[tid]);
      float zz = sigm(s_i[Hh + tid]  + s_g[Hh + tid]);
      float n  = tanhf(s_i[2*Hh+tid] + r*(s_g[2*Hh+tid] + s_bn[tid]));
      s_h[tid] = n + zz*(s_h[tid] - n);
    }
    __syncthreads();
    if (mode == 0){
      if (tid < Hh){
        int o = tid >> 4, m = tid & 15;
        float p = 0.f;
        #pragma unroll
        for (int q = 0; q < 8; q++) p += s_zxlw[o*Hh + m*8 + q]*s_h[m*8 + q];
        s_red[o][m] = p;
      }
      __syncthreads();
      if (tid < NZ){
        float p = zxlb[tid];
        #pragma unroll
        for (int m = 0; m < 16; m++) p += s_red[tid][m];
        out_zx[(size_t)b*Tt*NZ + (size_t)t*NZ + tid] = p;
      }
      __syncthreads();
    }
  }
  if (mode == 1 && tid < Hh) out_h[b*Hh + tid] = s_h[tid];
}

// ---------------- CDE RK4 v8 — round-11 base + phase-A folded into B ----------
// 256 blocks (1/CU) x 2 batches x 512 threads. 4 barriers/stage (was 5).
__global__ __launch_bounds__(512)
__attribute__((amdgpu_waves_per_eu(2, 2)))
void cde_fp32_kernel(
    const float* __restrict__ zy_h, const float* __restrict__ zx,
    const float* __restrict__ tin,
    const float* __restrict__ fw1, const float* __restrict__ fb1,
    const float* __restrict__ fw2, const float* __restrict__ fb2,
    const float* __restrict__ fw3, const float* __restrict__ fb3,
    const float* __restrict__ rw,  const float* __restrict__ rb,
    float* __restrict__ yout)
{
  const int tid = threadIdx.x;
  const int c12 = tid >> 2;      // G1/G2: output col 0..127
  const int q4  = tid & 3;       // G1/G2: k-quarter
  const int col64 = tid >> 3;    // G3: col-in-group 0..63
  const int e8    = tid & 7;     // G3: k-eighth (16 floats)
  const int bg = blockIdx.x * BBt;

  __shared__ __align__(16) float4 s_w1v[4096];   // 64 KB, [jj][col*4+q4]
  __shared__ __align__(16) float4 s_w2v[4096];   // 64 KB
  __shared__ __align__(16) float4 s_zinv[BBt][32];  // swizzled state rows
  __shared__ __align__(16) float4 s_h1v[BBt][32];
  __shared__ __align__(16) float4 s_h2v[BBt][32];
  __shared__ float s_o[BBt][W3N];                // raw pre-activations
  __shared__ float s_z[BBt][Hh];
  __shared__ float s_kacc[BBt][Hh];
  __shared__ float s_dx[BBt][CF];
  __shared__ float s_rw[OC*Hh];
  __shared__ float s_rb[OC];
  __shared__ float s_b3[W3N];

  float* zin_f0 = reinterpret_cast<float*>(&s_zinv[0][0]);
  float* zin_f1 = reinterpret_cast<float*>(&s_zinv[1][0]);
  float* h1_f0  = reinterpret_cast<float*>(&s_h1v[0][0]);
  float* h1_f1  = reinterpret_cast<float*>(&s_h1v[1][0]);
  float* h2_f0  = reinterpret_cast<float*>(&s_h2v[0][0]);
  float* h2_f1  = reinterpret_cast<float*>(&s_h2v[1][0]);

  // ---- one-time: w1/w2 -> [jj][col*4+q] layout; biases, readout, init ----
  for (int idx = tid; idx < Hh*32; idx += 512){
    int col = idx >> 5, jcol = idx & 31;
    int q = jcol >> 3, jj = jcol & 7;
    int dst = jj*512 + col*4 + q;
    s_w1v[dst] = reinterpret_cast<const float4*>(fw1)[idx];
    s_w2v[dst] = reinterpret_cast<const float4*>(fw2)[idx];
  }
  const float b1r = fb1[c12], b2r = fb2[c12];
  for (int idx = tid; idx < W3N; idx += 512) s_b3[idx] = fb3[idx];
  for (int idx = tid; idx < OC*Hh; idx += 512) s_rw[idx] = rw[idx];
  if (tid < OC) s_rb[tid] = rb[tid];
  if (tid < BBt*Hh){
    int b = tid >> 7, h = tid & 127;
    float zv = zy_h[(size_t)(bg + b)*Hh + h];
    s_z[b][h] = zv;
    (b == 0 ? zin_f0 : zin_f1)[swzf(h)] = zv;
  }
  __syncthreads();

  // y[:, 0, :]
  if (tid < 256){
    int b = tid >> 7, r = tid & 127, o = r >> 4, seg = r & 15;
    float p = 0.f;
    #pragma unroll
    for (int q = 0; q < 8; q++)
      p += s_z[b][seg*8 + q]*s_rw[o*Hh + seg*8 + q];
    p += __shfl_xor(p, 1, 64); p += __shfl_xor(p, 2, 64);
    p += __shfl_xor(p, 4, 64); p += __shfl_xor(p, 8, 64);
    if (seg == 0) yout[(size_t)(bg + b)*Ff*OC + o] = s_rb[o] + p;
  }

  const float* w3p = fw3 + (size_t)col64*Hh + e8*16;   // + g*8192 floats per iter

  for (int i = 0; i < Ff - 1; i++){
    if (tid < BBt*CF){
      int b = tid/CF, c = tid%CF;
      float d;
      if (c < 8){
        const float* zp = zx + (size_t)(bg + b)*Tt*NZ + (size_t)(Ll + i)*NZ + c;
        d = zp[NZ] - zp[0];
      } else {
        d = tin[Ll + i + 1] - tin[Ll + i];
      }
      s_dx[b][c] = d;
    }
    __syncthreads();

    for (int st = 0; st < 4; st++){
      // ---- issue w3 iters 0,1 now; latency hides under G1/G2 ----
      float4 A0, A1, A2, A3, B0, B1, B2, B3;
      {
        const float4* pA = reinterpret_cast<const float4*>(w3p);
        const float4* pB = reinterpret_cast<const float4*>(w3p + 8192);
        A0 = pA[0]; A1 = pA[1]; A2 = pA[2]; A3 = pA[3];
        B0 = pB[0]; B1 = pB[1]; B2 = pB[2]; B3 = pB[3];
      }
      // ---- G1: h1 = softplus(zin @ w1.T + b1) ----
      {
        float p0 = 0.f, p1 = 0.f;
        #pragma unroll
        for (int jj = 0; jj < 8; jj++){
          float4 z0 = s_zinv[0][swz32(q4*8 + jj)];
          float4 z1 = s_zinv[1][swz32(q4*8 + jj)];
          float4 w = s_w1v[jj*512 + tid];
          p0 += dot4(w, z0); p1 += dot4(w, z1);
        }
        p0 += __shfl_xor(p0, 1, 64); p0 += __shfl_xor(p0, 2, 64);
        p1 += __shfl_xor(p1, 1, 64); p1 += __shfl_xor(p1, 2, 64);
        if (q4 == 0){
          h1_f0[swzf(c12)] = softplus_(b1r + p0);
          h1_f1[swzf(c12)] = softplus_(b1r + p1);
        }
      }
      __syncthreads();
      // ---- G2 ----
      {
        float p0 = 0.f, p1 = 0.f;
        #pragma unroll
        for (int jj = 0; jj < 8; jj++){
          float4 z0 = s_h1v[0][swz32(q4*8 + jj)];
          float4 z1 = s_h1v[1][swz32(q4*8 + jj)];
          float4 w = s_w2v[jj*512 + tid];
          p0 += dot4(w, z0); p1 += dot4(w, z1);
        }
        p0 += __shfl_xor(p0, 1, 64); p0 += __shfl_xor(p0, 2, 64);
        p1 += __shfl_xor(p1, 1, 64); p1 += __shfl_xor(p1, 2, 64);
        if (q4 == 0){
          h2_f0[swzf(c12)] = softplus_(b2r + p0);
          h2_f1[swzf(c12)] = softplus_(b2r + p1);
        }
      }
      __syncthreads();
      // ---- G3: 18 iters of 64 cols; wide stream, A/B pipeline (raw to s_o) ----
      {
        float4 h2a0 = s_h2v[0][swz32(e8*4 + 0)];
        float4 h2a1 = s_h2v[0][swz32(e8*4 + 1)];
        float4 h2a2 = s_h2v[0][swz32(e8*4 + 2)];
        float4 h2a3 = s_h2v[0][swz32(e8*4 + 3)];
        float4 h2b0 = s_h2v[1][swz32(e8*4 + 0)];
        float4 h2b1 = s_h2v[1][swz32(e8*4 + 1)];
        float4 h2b2 = s_h2v[1][swz32(e8*4 + 2)];
        float4 h2b3 = s_h2v[1][swz32(e8*4 + 3)];
        #pragma unroll 2
        for (int g = 0; g < 18; g++){
          float4 c0, c1, c2, c3;
          if ((g & 1) == 0){
            c0 = A0; c1 = A1; c2 = A2; c3 = A3;
            if (g + 2 < 18){
              const float4* pF = reinterpret_cast<const float4*>(w3p + (size_t)(g+2)*8192);
              A0 = pF[0]; A1 = pF[1]; A2 = pF[2]; A3 = pF[3];
            }
          } else {
            c0 = B0; c1 = B1; c2 = B2; c3 = B3;
            if (g + 2 < 18){
              const float4* pF = reinterpret_cast<const float4*>(w3p + (size_t)(g+2)*8192);
              B0 = pF[0]; B1 = pF[1]; B2 = pF[2]; B3 = pF[3];
            }
          }
          float p0 = dot4(c0, h2a0) + dot4(c1, h2a1) + dot4(c2, h2a2) + dot4(c3, h2a3);
          float p1 = dot4(c0, h2b0) + dot4(c1, h2b1) + dot4(c2, h2b2) + dot4(c3, h2b3);
          p0 += __shfl_xor(p0, 1, 64); p0 += __shfl_xor(p0, 2, 64); p0 += __shfl_xor(p0, 4, 64);
          p1 += __shfl_xor(p1, 1, 64); p1 += __shfl_xor(p1, 2, 64); p1 += __shfl_xor(p1, 4, 64);
          if (e8 == 0){
            int n = g*64 + col64;
            s_o[0][n] = s_b3[n] + p0;
            s_o[1][n] = s_b3[n] + p1;
          }
        }
      }
      __syncthreads();
      // ---- phase B (A folded in): k_h = sum_c tanh(raw)*dx + RK4 combine ----
      if (tid < BBt*Hh){
        int b = tid >> 7, h = tid & 127;
        float kc = 0.f;
        #pragma unroll
        for (int c = 0; c < CF; c++)
          kc += tanhf(s_o[b][h*CF + c]) * s_dx[b][c];
        float zv = s_z[b][h], zin;
        if      (st == 0){ s_kacc[b][h] = kc;        zin = zv + 0.5f*kc; }
        else if (st == 1){ s_kacc[b][h] += 2.f*kc;   zin = zv + 0.5f*kc; }
        else if (st == 2){ s_kacc[b][h] += 2.f*kc;   zin = zv + kc; }
        else { float zn = zv + (s_kacc[b][h] + kc)*(1.f/6.f); s_z[b][h] = zn; zin = zn; }
        (b == 0 ? zin_f0 : zin_f1)[swzf(h)] = zin;
      }
      __syncthreads();
    }
    // readout y[:, i+1, :]
    if (tid < 256){
      int b = tid >> 7, r = tid & 127, o = r >> 4, seg = r & 15;
      float p = 0.f;
      #pragma unroll
      for (int q = 0; q < 8; q++)
        p += s_z[b][seg*8 + q]*s_rw[o*Hh + seg*8 + q];
      p += __shfl_xor(p, 1, 64); p += __shfl_xor(p, 2, 64);
      p += __shfl_xor(p, 4, 64); p += __shfl_xor(p, 8, 64);
      if (seg == 0) yout[(size_t)(bg + b)*Ff*OC + (size_t)(i + 1)*OC + o] = s_rb[o] + p;
    }
  }
}

extern "C" void kernel_launch(void* const* d_in, const int* in_sizes, int n_in,
                              void* d_out, int out_size, void* d_ws, size_t ws_size,
                              hipStream_t stream)
{
  (void)in_sizes; (void)n_in; (void)out_size; (void)ws_size;
  const float* y_past = (const float*)d_in[0];
  const float* t_in   = (const float*)d_in[1];
  const float* coeffs = (const float*)d_in[2];
  // d_in[3] = input_length (fixed 256)
  const float* zx_wih = (const float*)d_in[4];
  const float* zx_whh = (const float*)d_in[5];
  const float* zx_b   = (const float*)d_in[6];
  const float* zx_bn  = (const float*)d_in[7];
  const float* zxl_w  = (const float*)d_in[8];
  const float* zxl_b  = (const float*)d_in[9];
  const float* zy_wih = (const float*)d_in[10];
  const float* zy_whh = (const float*)d_in[11];
  const float* zy_b   = (const float*)d_in[12];
  const float* zy_bn  = (const float*)d_in[13];
  const float* fw1 = (const float*)d_in[14];
  const float* fb1 = (const float*)d_in[15];
  const float* fw2 = (const float*)d_in[16];
  const float* fb2 = (const float*)d_in[17];
  const float* fw3 = (const float*)d_in[18];
  const float* fb3 = (const float*)d_in[19];
  const float* r_w = (const float*)d_in[20];
  const float* r_b = (const float*)d_in[21];

  float* ws = (float*)d_ws;
  float* zx_buf = ws;                              // B*T*NZ fp32 = 8.39 MB
  float* zy_buf = ws + (size_t)Bb*Tt*NZ;           // B*H fp32   = 256 KB

  gru_kernel<<<Bb, 768, 0, stream>>>(coeffs, nullptr, t_in,
                                     zx_wih, zx_whh, zx_b, zx_bn,
                                     zxl_w, zxl_b, zx_buf, nullptr, Tt, 0);
  gru_kernel<<<Bb, 768, 0, stream>>>(y_past, zx_buf, t_in,
                                     zy_wih, zy_whh, zy_b, zy_bn,
                                     nullptr, nullptr, nullptr, zy_buf, Ll, 1);
  cde_fp32_kernel<<<Bb/BBt, 512, 0, stream>>>(zy_buf, zx_buf, t_in,
                                              fw1, fb1, fw2, fb2, fw3, fb3,
                                              r_w, r_b, (float*)d_out);
}